// Round 1
// 336.000 us; speedup vs baseline: 1.0113x; 1.0113x over previous
//
#include <hip/hip_runtime.h>
#include <hip/hip_bf16.h>
#include <cstdint>
#include <cstddef>

#define T_DIM 1024
#define S_DIM 1024
#define N_HEADS 32
#define D_HEAD 128

typedef __attribute__((ext_vector_type(8))) short short8;
typedef __attribute__((ext_vector_type(4))) float floatx4;

__device__ inline int pack_bf16(float a, float b) {
    __hip_bfloat162 h = __float22bfloat162_rn(make_float2(a, b));
    int r; __builtin_memcpy(&r, &h, 4); return r;
}
__device__ inline ushort f2b(float x) {
    __hip_bfloat16 h = __float2bfloat16(x);
    ushort u; __builtin_memcpy(&u, &h, 2); return u;
}
__device__ inline float b2f(ushort u) {
    unsigned int v = ((unsigned int)u) << 16;
    float f; __builtin_memcpy(&f, &v, 4); return f;
}

// ---------------------------------------------------------------------------
// Vt[n][d][s] bf16 <- V[n][s][d] fp32.  64s x 128d tile per block. (unchanged)
// ---------------------------------------------------------------------------
__global__ __launch_bounds__(256) void vt_kernel(const float* __restrict__ V,
                                                 ushort* __restrict__ Vt) {
    const int s0 = blockIdx.x * 64;
    const int n  = blockIdx.y;
    __shared__ float lds[128 * 65];

    const int tid = threadIdx.x;
    const float* Vn = V + ((size_t)n * S_DIM + s0) * D_HEAD;

    #pragma unroll
    for (int it = 0; it < 8; ++it) {
        int idx = tid + it * 256;
        int d4 = idx & 31, s = idx >> 5;
        float4 v = *(const float4*)(Vn + (size_t)s * D_HEAD + d4 * 4);
        lds[(d4 * 4 + 0) * 65 + s] = v.x;
        lds[(d4 * 4 + 1) * 65 + s] = v.y;
        lds[(d4 * 4 + 2) * 65 + s] = v.z;
        lds[(d4 * 4 + 3) * 65 + s] = v.w;
    }
    __syncthreads();

    ushort* Vtn = Vt + (size_t)n * D_HEAD * S_DIM;
    #pragma unroll
    for (int it = 0; it < 4; ++it) {
        int idx = tid + it * 256;
        int sg = idx & 7, d = idx >> 3;
        const float* src = &lds[d * 65 + sg * 8];
        int4 o;
        o.x = pack_bf16(src[0], src[1]);
        o.y = pack_bf16(src[2], src[3]);
        o.z = pack_bf16(src[4], src[5]);
        o.w = pack_bf16(src[6], src[7]);
        *(int4*)&Vtn[(size_t)d * S_DIM + s0 + sg * 8] = o;
    }
}

// ---------------------------------------------------------------------------
// K1: logits (bf16) via MFMA, 64x64 causal tiles. (unchanged)
// ---------------------------------------------------------------------------
__global__ __launch_bounds__(256, 2) void qk_mfma(const float* __restrict__ Q,
                                                  const float* __restrict__ K,
                                                  ushort* __restrict__ Lb) {
    const int st = blockIdx.x;
    const int tt = blockIdx.y;
    const int n  = blockIdx.z;
    if (st > tt) return;

    __shared__ int Qt[64 * 64];
    __shared__ int Kt[64 * 64];

    const int tid = threadIdx.x;
    const int wv = tid >> 6, ln = tid & 63;
    const int frow = ln & 15, quad = ln >> 4;

    const float* Qn = Q + ((size_t)n * T_DIM + (size_t)tt * 64) * D_HEAD;
    const float* Kn = K + ((size_t)n * S_DIM + (size_t)st * 64) * D_HEAD;

    #pragma unroll
    for (int rep = 0; rep < 8; ++rep) {
        int idx = tid + rep * 256;
        int row = idx >> 5;
        int c4  = (idx & 31) * 4;
        int p   = c4 >> 1;
        int kb  = p >> 4, w = p & 15;
        int swz = 4 * (row & 3);
        float4 q = *(const float4*)(Qn + (size_t)row * D_HEAD + c4);
        int2 qv; qv.x = pack_bf16(q.x, q.y); qv.y = pack_bf16(q.z, q.w);
        *(int2*)&Qt[row * 64 + kb * 16 + (w ^ swz)] = qv;
        float4 k = *(const float4*)(Kn + (size_t)row * D_HEAD + c4);
        int2 kv; kv.x = pack_bf16(k.x, k.y); kv.y = pack_bf16(k.z, k.w);
        *(int2*)&Kt[row * 64 + kb * 16 + (w ^ swz)] = kv;
    }
    __syncthreads();

    const int swz = 4 * (frow & 3);
    floatx4 acc[4] = {};
    #pragma unroll
    for (int kb = 0; kb < 4; ++kb) {
        const short8 af = *(const short8*)&Qt[(wv * 16 + frow) * 64 + kb * 16 + ((quad * 4) ^ swz)];
        #pragma unroll
        for (int si = 0; si < 4; ++si) {
            const short8 bf = *(const short8*)&Kt[(si * 16 + frow) * 64 + kb * 16 + ((quad * 4) ^ swz)];
            acc[si] = __builtin_amdgcn_mfma_f32_16x16x32_bf16(af, bf, acc[si], 0, 0, 0);
        }
    }
    __syncthreads();                    // Qt dead -> reuse as output tile

    ushort* Ot = (ushort*)Qt;           // [64][72] bf16
    #pragma unroll
    for (int si = 0; si < 4; ++si)
        #pragma unroll
        for (int r = 0; r < 4; ++r)
            Ot[(wv * 16 + quad * 4 + r) * 72 + si * 16 + frow] = f2b(acc[si][r]);
    __syncthreads();

    #pragma unroll
    for (int it = 0; it < 2; ++it) {
        int idx = tid + it * 256;
        int row = idx >> 3, col = idx & 7;
        int4 v = *(const int4*)&Ot[row * 72 + col * 8];
        *(int4*)&Lb[((size_t)n * T_DIM + tt * 64 + row) * S_DIM + st * 64 + col * 8] = v;
    }
}

// ---------------------------------------------------------------------------
// Precompute all four 32x32 mixing-matrix families in one launch. (unchanged)
// Layout of each mats family: [pos][n_out][m_in], m contiguous (bf16).
// ---------------------------------------------------------------------------
__global__ __launch_bounds__(256) void mat4_kernel(
        const float* __restrict__ sw_pre,  const float* __restrict__ qw1_pre,
        const float* __restrict__ qw2_pre, const float* __restrict__ qdd_pre,
        const float* __restrict__ kw1_pre, const float* __restrict__ kw2_pre,
        const float* __restrict__ kdd_pre,
        const float* __restrict__ sw_post,  const float* __restrict__ qw1_post,
        const float* __restrict__ qw2_post, const float* __restrict__ qdd_post,
        const float* __restrict__ kw1_post, const float* __restrict__ kw2_post,
        const float* __restrict__ kdd_post,
        ushort* __restrict__ mats) {
    const float *sw, *w1, *w2, *dd;
    float idadd;
    switch (blockIdx.y) {
        case 0:  sw = sw_pre;  w1 = qw1_pre;  w2 = qw2_pre;  dd = qdd_pre;  idadd = 1.0f; break;
        case 1:  sw = nullptr; w1 = kw1_pre;  w2 = kw2_pre;  dd = kdd_pre;  idadd = 0.0f; break;
        case 2:  sw = sw_post; w1 = qw1_post; w2 = qw2_post; dd = qdd_post; idadd = 1.0f; break;
        default: sw = nullptr; w1 = kw1_post; w2 = kw2_post; dd = kdd_post; idadd = 0.0f; break;
    }
    ushort* out = mats + (size_t)blockIdx.y * 1024 * 1024;

    const int t = blockIdx.x;
    const int tid = threadIdx.x;
    const int m = tid >> 3;
    const int n0 = (tid & 7) * 4;

    const float w2m0 = w2[t * 64 + m];
    const float w2m1 = w2[t * 64 + 32 + m];
    const float ddm  = dd[t * 32 + m];

    float v[4];
    #pragma unroll
    for (int j = 0; j < 4; ++j) {
        int n = n0 + j;
        float r = w1[t * 64 + n] * w2m0 + w1[t * 64 + 32 + n] * w2m1;
        if (sw) r += sw[n * 32 + m];
        if (n == m) r += idadd + ddm;
        v[j] = r;
    }
    int p0 = pack_bf16(v[0], v[1]);
    int p1 = pack_bf16(v[2], v[3]);
    int2 st = make_int2(p0, p1);
    *(int2*)&out[(size_t)t * 1024 + m * 32 + n0] = st;
}

// ---------------------------------------------------------------------------
// proj2: fused cross-head projection, 16t x 32s x all-32-heads per block.
// X staged with coalesced uint4 row loads (64 B runs) -> padded LDS [t][s][m]
// (s-stride 40 ush = 80 B, t-stride 1288 ush = 2576 B: both MFMA fragment
// read patterns land 8 consecutive lanes on 8 distinct 16 B bank slots).
// K-side partial in f32 Kp[t][s][n] (t-stride 516 f32): b128 writes are
// conflict-free (slot = frow+quad mod 8), scalar reads <=4-way.
// Same operand orientations as the previous verified proj_mfma.
// ---------------------------------------------------------------------------
__global__ __launch_bounds__(256, 2) void proj2(ushort* __restrict__ Lb,
                                                const ushort* __restrict__ Cmat,
                                                const ushort* __restrict__ Kmat) {
    const int s0 = blockIdx.x * 32;
    const int t0 = blockIdx.y * 16;
    if (s0 > t0 + 15) return;

    __shared__ __align__(16) ushort Xs[16 * 1288];   // 41216 B
    __shared__ __align__(16) float  Kp[16 * 516];    // 33024 B  (total 74240 B -> 2 blocks/CU)

    const int tid = threadIdx.x;
    const int wv = tid >> 6, ln = tid & 63;
    const int frow = ln & 15, quad = ln >> 4;

    // ---- stage X[t][s][m] <- Lb[m][t0+t][s0+s] (transpose head -> contiguous)
    #pragma unroll
    for (int it = 0; it < 8; ++it) {
        int slot = tid + it * 256;           // 2048 slots = 512 rows x 4 chunks
        int c    = slot & 3;                 // 16 B chunk -> 8 s values
        int row  = slot >> 2;                // n*16 + t
        int nn   = row >> 4, tl = row & 15;
        uint4 ld = *(const uint4*)(Lb + ((size_t)nn * T_DIM + t0 + tl) * S_DIM + s0 + c * 8);
        ushort* xp = &Xs[tl * 1288 + (c * 8) * 40 + nn];
        uint w0 = ld.x, w1 = ld.y, w2 = ld.z, w3 = ld.w;
        xp[0 * 40] = (ushort)(w0 & 0xffff);  xp[1 * 40] = (ushort)(w0 >> 16);
        xp[2 * 40] = (ushort)(w1 & 0xffff);  xp[3 * 40] = (ushort)(w1 >> 16);
        xp[4 * 40] = (ushort)(w2 & 0xffff);  xp[5 * 40] = (ushort)(w2 >> 16);
        xp[6 * 40] = (ushort)(w3 & 0xffff);  xp[7 * 40] = (ushort)(w3 >> 16);
    }
    __syncthreads();

    #pragma unroll
    for (int mh = 0; mh < 2; ++mh) {
        // ---- K-phase: per s, D[n=16][t=16] = Kmat[s](n,m) x X(m,t,s); K=m=32
        #pragma unroll
        for (int k = 0; k < 8; ++k) {
            const int sl = wv * 8 + k;
            const short8 af = *(const short8*)(Kmat + (size_t)(s0 + sl) * 1024 + (mh * 16 + frow) * 32 + quad * 8);
            const short8 bf = *(const short8*)&Xs[frow * 1288 + sl * 40 + quad * 8];
            floatx4 z = {0.f, 0.f, 0.f, 0.f};
            floatx4 d = __builtin_amdgcn_mfma_f32_16x16x32_bf16(af, bf, z, 0, 0, 0);
            // D rows (quad*4+r) = n, cols (frow) = t  ->  Kp[t][s][n]
            *(floatx4*)&Kp[frow * 516 + sl * 16 + quad * 4] = d;
        }
        __syncthreads();

        // ---- C-phase: per t, D[s=16][n=16] = X(s,m,t) x Cmat[t](n,m); add Kp, mask, store
        #pragma unroll
        for (int i = 0; i < 4; ++i) {
            const int tl = wv * 4 + i;
            const int tg = t0 + tl;
            const short8 bf = *(const short8*)(Cmat + (size_t)tg * 1024 + (mh * 16 + frow) * 32 + quad * 8);
            #pragma unroll
            for (int st = 0; st < 2; ++st) {
                const short8 af = *(const short8*)&Xs[tl * 1288 + (st * 16 + frow) * 40 + quad * 8];
                floatx4 z = {0.f, 0.f, 0.f, 0.f};
                floatx4 d = __builtin_amdgcn_mfma_f32_16x16x32_bf16(af, bf, z, 0, 0, 0);
                // D rows (quad*4+r) = s_local, cols (frow) = n
                float v[4];
                #pragma unroll
                for (int r = 0; r < 4; ++r) {
                    const int sl = st * 16 + quad * 4 + r;
                    float val = d[r] + Kp[tl * 516 + sl * 16 + frow];
                    v[r] = (s0 + sl > tg) ? 0.0f : val;
                }
                uint2 stv;
                stv.x = (unsigned)pack_bf16(v[0], v[1]);
                stv.y = (unsigned)pack_bf16(v[2], v[3]);
                *(uint2*)&Lb[((size_t)(mh * 16 + frow) * T_DIM + tg) * S_DIM + s0 + st * 16 + quad * 4] = stv;
            }
        }
        __syncthreads();   // Kp reused by next mh
    }
}

// ---------------------------------------------------------------------------
// softmax2: one WAVE per row, 4 rows/block, shuffle-only reductions, no LDS,
// no barriers. uint4 (8 bf16) loads/stores. Causal skip as before.
// ---------------------------------------------------------------------------
__global__ __launch_bounds__(256) void softmax2(ushort* __restrict__ Lb) {
    const int wv = threadIdx.x >> 6;
    const int ln = threadIdx.x & 63;
    const int r0 = blockIdx.x * 4 + wv;       // n*1024 + t
    const int t  = r0 & (T_DIM - 1);
    ushort* row = Lb + (size_t)r0 * S_DIM;

    float v[2][8];
    #pragma unroll
    for (int it = 0; it < 2; ++it) {
        const int i0 = it * 512 + ln * 8;
        #pragma unroll
        for (int j = 0; j < 8; ++j) v[it][j] = -INFINITY;
        if (i0 <= t) {
            uint4 raw = *(const uint4*)&row[i0];
            v[it][0] = b2f((ushort)(raw.x & 0xffff)); v[it][1] = b2f((ushort)(raw.x >> 16));
            v[it][2] = b2f((ushort)(raw.y & 0xffff)); v[it][3] = b2f((ushort)(raw.y >> 16));
            v[it][4] = b2f((ushort)(raw.z & 0xffff)); v[it][5] = b2f((ushort)(raw.z >> 16));
            v[it][6] = b2f((ushort)(raw.w & 0xffff)); v[it][7] = b2f((ushort)(raw.w >> 16));
            #pragma unroll
            for (int j = 0; j < 8; ++j)
                if (i0 + j > t) v[it][j] = -INFINITY;
        }
    }

    float m = -INFINITY;
    #pragma unroll
    for (int it = 0; it < 2; ++it)
        #pragma unroll
        for (int j = 0; j < 8; ++j) m = fmaxf(m, v[it][j]);
    #pragma unroll
    for (int off = 32; off > 0; off >>= 1) m = fmaxf(m, __shfl_xor(m, off));

    float ssum = 0.0f;
    #pragma unroll
    for (int it = 0; it < 2; ++it)
        #pragma unroll
        for (int j = 0; j < 8; ++j) {
            float e = (v[it][j] > -1e37f) ? __expf(v[it][j] - m) : 0.0f;
            v[it][j] = e;
            ssum += e;
        }
    #pragma unroll
    for (int off = 32; off > 0; off >>= 1) ssum += __shfl_xor(ssum, off);
    const float inv = 1.0f / ssum;

    #pragma unroll
    for (int it = 0; it < 2; ++it) {
        const int i0 = it * 512 + ln * 8;
        if (i0 <= t) {
            uint4 stv;
            stv.x = (unsigned)pack_bf16(v[it][0] * inv, v[it][1] * inv);
            stv.y = (unsigned)pack_bf16(v[it][2] * inv, v[it][3] * inv);
            stv.z = (unsigned)pack_bf16(v[it][4] * inv, v[it][5] * inv);
            stv.w = (unsigned)pack_bf16(v[it][6] * inv, v[it][7] * inv);
            *(uint4*)&row[i0] = stv;
        }
    }
}

// ---------------------------------------------------------------------------
// av2: O = P V via MFMA, barrier-free and LDS-free. One WAVE owns one
// (n, 16-row t-tile); A-frags read directly from P (64 B/row per instr,
// sector-coalesced, LLC-hot), B-frags from Vt as before. Full f32
// accumulation, direct f32 stores (64 B runs) -- no bf16 partial rounding.
// ---------------------------------------------------------------------------
__global__ __launch_bounds__(256, 4) void av2(const ushort* __restrict__ P,
                                              const ushort* __restrict__ Vt,
                                              float* __restrict__ O) {
    const int wv = threadIdx.x >> 6, ln = threadIdx.x & 63;
    const int frow = ln & 15, quad = ln >> 4;
    const int tt = 63 - (blockIdx.x * 4 + wv);   // big tiles first
    const int n  = blockIdx.y;
    const int t0 = tt * 16;

    const ushort* Pn  = P  + ((size_t)n * T_DIM + t0) * S_DIM;
    const ushort* Vtn = Vt + (size_t)n * D_HEAD * S_DIM;

    const int nsteps = (t0 + 47) >> 5;   // ceil((t0+16)/32)
    const int nclean = t0 >> 5;          // steps fully below diagonal

    floatx4 acc[8] = {};
    for (int sb = 0; sb < nsteps; ++sb) {
        short8 a = *(const short8*)(Pn + (size_t)frow * S_DIM + sb * 32 + quad * 8);
        if (sb >= nclean) {
            const int tg  = t0 + frow;
            const int sg0 = sb * 32 + quad * 8;
            #pragma unroll
            for (int j = 0; j < 8; ++j)
                if (sg0 + j > tg) a[j] = 0;
        }
        #pragma unroll
        for (int dc = 0; dc < 8; ++dc) {
            const short8 b = *(const short8*)(Vtn + (size_t)(dc * 16 + frow) * S_DIM + sb * 32 + quad * 8);
            acc[dc] = __builtin_amdgcn_mfma_f32_16x16x32_bf16(a, b, acc[dc], 0, 0, 0);
        }
    }

    float* On = O + ((size_t)n * T_DIM + t0) * D_HEAD;
    #pragma unroll
    for (int dc = 0; dc < 8; ++dc)
        #pragma unroll
        for (int r = 0; r < 4; ++r)
            On[(size_t)(quad * 4 + r) * D_HEAD + dc * 16 + frow] = acc[dc][r];
}

// ---------------------------------------------------------------------------
extern "C" void kernel_launch(void* const* d_in, const int* in_sizes, int n_in,
                              void* d_out, int out_size, void* d_ws, size_t ws_size,
                              hipStream_t stream) {
    const float* Q    = (const float*)d_in[0];
    const float* K    = (const float*)d_in[1];
    const float* V    = (const float*)d_in[2];
    const float* sw_pre  = (const float*)d_in[4];
    const float* qw1_pre = (const float*)d_in[5];
    const float* qw2_pre = (const float*)d_in[6];
    const float* kw1_pre = (const float*)d_in[7];
    const float* kw2_pre = (const float*)d_in[8];
    const float* qdd_pre = (const float*)d_in[9];
    const float* kdd_pre = (const float*)d_in[10];
    const float* sw_post  = (const float*)d_in[11];
    const float* qw1_post = (const float*)d_in[12];
    const float* qw2_post = (const float*)d_in[13];
    const float* kw1_post = (const float*)d_in[14];
    const float* kw2_post = (const float*)d_in[15];
    const float* qdd_post = (const float*)d_in[16];
    const float* kdd_post = (const float*)d_in[17];

    // ws: L bf16 [32][1024][1024] = 64 MB, then Vt bf16 [32][128][1024] = 8 MB
    ushort* Lb = (ushort*)d_ws;
    ushort* Vt = (ushort*)((char*)d_ws + (size_t)N_HEADS * T_DIM * S_DIM * 2);
    float*  O  = (float*)d_out;

    // mats in d_out (8 MB of 16), consumed before av overwrites d_out
    ushort* mats  = (ushort*)d_out;
    ushort* Cpre  = mats + 0 * 1024 * 1024;
    ushort* Kpre  = mats + 1 * 1024 * 1024;
    ushort* Cpost = mats + 2 * 1024 * 1024;
    ushort* Kpost = mats + 3 * 1024 * 1024;

    mat4_kernel<<<dim3(1024, 4), 256, 0, stream>>>(
        sw_pre, qw1_pre, qw2_pre, qdd_pre, kw1_pre, kw2_pre, kdd_pre,
        sw_post, qw1_post, qw2_post, qdd_post, kw1_post, kw2_post, kdd_post, mats);
    vt_kernel<<<dim3(16, 32), 256, 0, stream>>>(V, Vt);

    qk_mfma<<<dim3(16, 16, 32), 256, 0, stream>>>(Q, K, Lb);
    proj2<<<dim3(32, 64), 256, 0, stream>>>(Lb, Cpre, Kpre);
    softmax2<<<dim3(8192), 256, 0, stream>>>(Lb);
    proj2<<<dim3(32, 64), 256, 0, stream>>>(Lb, Cpost, Kpost);
    av2<<<dim3(16, 32), 256, 0, stream>>>(Lb, Vt, O);
}

// Round 2
// 294.121 us; speedup vs baseline: 1.1553x; 1.1424x over previous
//
#include <hip/hip_runtime.h>
#include <hip/hip_bf16.h>
#include <cstdint>
#include <cstddef>

#define T_DIM 1024
#define S_DIM 1024
#define N_HEADS 32
#define D_HEAD 128

typedef __attribute__((ext_vector_type(8))) short short8;
typedef __attribute__((ext_vector_type(4))) float floatx4;

__device__ inline int pack_bf16(float a, float b) {
    __hip_bfloat162 h = __float22bfloat162_rn(make_float2(a, b));
    int r; __builtin_memcpy(&r, &h, 4); return r;
}
__device__ inline ushort f2b(float x) {
    __hip_bfloat16 h = __float2bfloat16(x);
    ushort u; __builtin_memcpy(&u, &h, 2); return u;
}
__device__ inline float b2f(ushort u) {
    unsigned int v = ((unsigned int)u) << 16;
    float f; __builtin_memcpy(&f, &v, 4); return f;
}

// ---------------------------------------------------------------------------
// Vt[n][d][s] bf16 <- V[n][s][d] fp32.  64s x 128d tile per block. (unchanged)
// ---------------------------------------------------------------------------
__global__ __launch_bounds__(256) void vt_kernel(const float* __restrict__ V,
                                                 ushort* __restrict__ Vt) {
    const int s0 = blockIdx.x * 64;
    const int n  = blockIdx.y;
    __shared__ float lds[128 * 65];

    const int tid = threadIdx.x;
    const float* Vn = V + ((size_t)n * S_DIM + s0) * D_HEAD;

    #pragma unroll
    for (int it = 0; it < 8; ++it) {
        int idx = tid + it * 256;
        int d4 = idx & 31, s = idx >> 5;
        float4 v = *(const float4*)(Vn + (size_t)s * D_HEAD + d4 * 4);
        lds[(d4 * 4 + 0) * 65 + s] = v.x;
        lds[(d4 * 4 + 1) * 65 + s] = v.y;
        lds[(d4 * 4 + 2) * 65 + s] = v.z;
        lds[(d4 * 4 + 3) * 65 + s] = v.w;
    }
    __syncthreads();

    ushort* Vtn = Vt + (size_t)n * D_HEAD * S_DIM;
    #pragma unroll
    for (int it = 0; it < 4; ++it) {
        int idx = tid + it * 256;
        int sg = idx & 7, d = idx >> 3;
        const float* src = &lds[d * 65 + sg * 8];
        int4 o;
        o.x = pack_bf16(src[0], src[1]);
        o.y = pack_bf16(src[2], src[3]);
        o.z = pack_bf16(src[4], src[5]);
        o.w = pack_bf16(src[6], src[7]);
        *(int4*)&Vtn[(size_t)d * S_DIM + s0 + sg * 8] = o;
    }
}

// ---------------------------------------------------------------------------
// K1: logits (bf16) via MFMA, 64x64 causal tiles. (unchanged)
// ---------------------------------------------------------------------------
__global__ __launch_bounds__(256, 2) void qk_mfma(const float* __restrict__ Q,
                                                  const float* __restrict__ K,
                                                  ushort* __restrict__ Lb) {
    const int st = blockIdx.x;
    const int tt = blockIdx.y;
    const int n  = blockIdx.z;
    if (st > tt) return;

    __shared__ int Qt[64 * 64];
    __shared__ int Kt[64 * 64];

    const int tid = threadIdx.x;
    const int wv = tid >> 6, ln = tid & 63;
    const int frow = ln & 15, quad = ln >> 4;

    const float* Qn = Q + ((size_t)n * T_DIM + (size_t)tt * 64) * D_HEAD;
    const float* Kn = K + ((size_t)n * S_DIM + (size_t)st * 64) * D_HEAD;

    #pragma unroll
    for (int rep = 0; rep < 8; ++rep) {
        int idx = tid + rep * 256;
        int row = idx >> 5;
        int c4  = (idx & 31) * 4;
        int p   = c4 >> 1;
        int kb  = p >> 4, w = p & 15;
        int swz = 4 * (row & 3);
        float4 q = *(const float4*)(Qn + (size_t)row * D_HEAD + c4);
        int2 qv; qv.x = pack_bf16(q.x, q.y); qv.y = pack_bf16(q.z, q.w);
        *(int2*)&Qt[row * 64 + kb * 16 + (w ^ swz)] = qv;
        float4 k = *(const float4*)(Kn + (size_t)row * D_HEAD + c4);
        int2 kv; kv.x = pack_bf16(k.x, k.y); kv.y = pack_bf16(k.z, k.w);
        *(int2*)&Kt[row * 64 + kb * 16 + (w ^ swz)] = kv;
    }
    __syncthreads();

    const int swz = 4 * (frow & 3);
    floatx4 acc[4] = {};
    #pragma unroll
    for (int kb = 0; kb < 4; ++kb) {
        const short8 af = *(const short8*)&Qt[(wv * 16 + frow) * 64 + kb * 16 + ((quad * 4) ^ swz)];
        #pragma unroll
        for (int si = 0; si < 4; ++si) {
            const short8 bf = *(const short8*)&Kt[(si * 16 + frow) * 64 + kb * 16 + ((quad * 4) ^ swz)];
            acc[si] = __builtin_amdgcn_mfma_f32_16x16x32_bf16(af, bf, acc[si], 0, 0, 0);
        }
    }
    __syncthreads();                    // Qt dead -> reuse as output tile

    ushort* Ot = (ushort*)Qt;           // [64][72] bf16
    #pragma unroll
    for (int si = 0; si < 4; ++si)
        #pragma unroll
        for (int r = 0; r < 4; ++r)
            Ot[(wv * 16 + quad * 4 + r) * 72 + si * 16 + frow] = f2b(acc[si][r]);
    __syncthreads();

    #pragma unroll
    for (int it = 0; it < 2; ++it) {
        int idx = tid + it * 256;
        int row = idx >> 3, col = idx & 7;
        int4 v = *(const int4*)&Ot[row * 72 + col * 8];
        *(int4*)&Lb[((size_t)n * T_DIM + tt * 64 + row) * S_DIM + st * 64 + col * 8] = v;
    }
}

// ---------------------------------------------------------------------------
// Precompute all four 32x32 mixing-matrix families in one launch. (unchanged)
// ---------------------------------------------------------------------------
__global__ __launch_bounds__(256) void mat4_kernel(
        const float* __restrict__ sw_pre,  const float* __restrict__ qw1_pre,
        const float* __restrict__ qw2_pre, const float* __restrict__ qdd_pre,
        const float* __restrict__ kw1_pre, const float* __restrict__ kw2_pre,
        const float* __restrict__ kdd_pre,
        const float* __restrict__ sw_post,  const float* __restrict__ qw1_post,
        const float* __restrict__ qw2_post, const float* __restrict__ qdd_post,
        const float* __restrict__ kw1_post, const float* __restrict__ kw2_post,
        const float* __restrict__ kdd_post,
        ushort* __restrict__ mats) {
    const float *sw, *w1, *w2, *dd;
    float idadd;
    switch (blockIdx.y) {
        case 0:  sw = sw_pre;  w1 = qw1_pre;  w2 = qw2_pre;  dd = qdd_pre;  idadd = 1.0f; break;
        case 1:  sw = nullptr; w1 = kw1_pre;  w2 = kw2_pre;  dd = kdd_pre;  idadd = 0.0f; break;
        case 2:  sw = sw_post; w1 = qw1_post; w2 = qw2_post; dd = qdd_post; idadd = 1.0f; break;
        default: sw = nullptr; w1 = kw1_post; w2 = kw2_post; dd = kdd_post; idadd = 0.0f; break;
    }
    ushort* out = mats + (size_t)blockIdx.y * 1024 * 1024;

    const int t = blockIdx.x;
    const int tid = threadIdx.x;
    const int m = tid >> 3;
    const int n0 = (tid & 7) * 4;

    const float w2m0 = w2[t * 64 + m];
    const float w2m1 = w2[t * 64 + 32 + m];
    const float ddm  = dd[t * 32 + m];

    float v[4];
    #pragma unroll
    for (int j = 0; j < 4; ++j) {
        int n = n0 + j;
        float r = w1[t * 64 + n] * w2m0 + w1[t * 64 + 32 + n] * w2m1;
        if (sw) r += sw[n * 32 + m];
        if (n == m) r += idadd + ddm;
        v[j] = r;
    }
    int p0 = pack_bf16(v[0], v[1]);
    int p1 = pack_bf16(v[2], v[3]);
    int2 st = make_int2(p0, p1);
    *(int2*)&out[(size_t)t * 1024 + m * 32 + n0] = st;
}

// ---------------------------------------------------------------------------
// rowstat: per-(n,t) softmax stats. One wave per row, 4 rows/block.
// Reads only s <= t (causal). Writes m and 1/sum as float2.
// ---------------------------------------------------------------------------
__global__ __launch_bounds__(256) void rowstat(const ushort* __restrict__ Lb,
                                               float2* __restrict__ stats) {
    const int wv = threadIdx.x >> 6;
    const int ln = threadIdx.x & 63;
    const int r0 = blockIdx.x * 4 + wv;       // n*1024 + t
    const int t  = r0 & (T_DIM - 1);
    const ushort* row = Lb + (size_t)r0 * S_DIM;

    float v[2][8];
    #pragma unroll
    for (int it = 0; it < 2; ++it) {
        const int i0 = it * 512 + ln * 8;
        #pragma unroll
        for (int j = 0; j < 8; ++j) v[it][j] = -INFINITY;
        if (i0 <= t) {
            uint4 raw = *(const uint4*)&row[i0];
            v[it][0] = b2f((ushort)(raw.x & 0xffff)); v[it][1] = b2f((ushort)(raw.x >> 16));
            v[it][2] = b2f((ushort)(raw.y & 0xffff)); v[it][3] = b2f((ushort)(raw.y >> 16));
            v[it][4] = b2f((ushort)(raw.z & 0xffff)); v[it][5] = b2f((ushort)(raw.z >> 16));
            v[it][6] = b2f((ushort)(raw.w & 0xffff)); v[it][7] = b2f((ushort)(raw.w >> 16));
            #pragma unroll
            for (int j = 0; j < 8; ++j)
                if (i0 + j > t) v[it][j] = -INFINITY;
        }
    }

    float m = -INFINITY;
    #pragma unroll
    for (int it = 0; it < 2; ++it)
        #pragma unroll
        for (int j = 0; j < 8; ++j) m = fmaxf(m, v[it][j]);
    #pragma unroll
    for (int off = 32; off > 0; off >>= 1) m = fmaxf(m, __shfl_xor(m, off));

    float ssum = 0.0f;
    #pragma unroll
    for (int it = 0; it < 2; ++it)
        #pragma unroll
        for (int j = 0; j < 8; ++j)
            ssum += (v[it][j] > -1e37f) ? __expf(v[it][j] - m) : 0.0f;
    #pragma unroll
    for (int off = 32; off > 0; off >>= 1) ssum += __shfl_xor(ssum, off);

    if (ln == 0) stats[r0] = make_float2(m, 1.0f / ssum);
}

// ---------------------------------------------------------------------------
// proj2t: fused cross-head projection, 16t x 32s x all-32-heads per block.
// SM=true additionally converts logits -> probs (exp(x-m)*inv, causal-zeroed)
// during staging, eliminating the separate softmax pass.
// ---------------------------------------------------------------------------
template<bool SM>
__global__ __launch_bounds__(256, 2) void proj2t(ushort* __restrict__ Lb,
                                                 const ushort* __restrict__ Cmat,
                                                 const ushort* __restrict__ Kmat,
                                                 const float2* __restrict__ stats) {
    const int s0 = blockIdx.x * 32;
    const int t0 = blockIdx.y * 16;
    if (s0 > t0 + 15) return;

    __shared__ __align__(16) ushort Xs[16 * 1288];   // 41216 B
    __shared__ __align__(16) float  Kp[16 * 516];    // 33024 B

    const int tid = threadIdx.x;
    const int wv = tid >> 6, ln = tid & 63;
    const int frow = ln & 15, quad = ln >> 4;

    // ---- stage X[t][s][m] <- Lb[m][t0+t][s0+s] (transpose head -> contiguous)
    #pragma unroll
    for (int it = 0; it < 8; ++it) {
        int slot = tid + it * 256;           // 2048 slots = 512 rows x 4 chunks
        int c    = slot & 3;                 // 16 B chunk -> 8 s values
        int row  = slot >> 2;                // n*16 + t
        int nn   = row >> 4, tl = row & 15;
        uint4 ld = *(const uint4*)(Lb + ((size_t)nn * T_DIM + t0 + tl) * S_DIM + s0 + c * 8);
        ushort u[8];
        u[0] = (ushort)(ld.x & 0xffff);  u[1] = (ushort)(ld.x >> 16);
        u[2] = (ushort)(ld.y & 0xffff);  u[3] = (ushort)(ld.y >> 16);
        u[4] = (ushort)(ld.z & 0xffff);  u[5] = (ushort)(ld.z >> 16);
        u[6] = (ushort)(ld.w & 0xffff);  u[7] = (ushort)(ld.w >> 16);
        if (SM) {
            const float2 ms = stats[nn * T_DIM + t0 + tl];
            const int tG = t0 + tl, sbase = s0 + c * 8;
            #pragma unroll
            for (int j = 0; j < 8; ++j) {
                float x = (sbase + j <= tG) ? __expf(b2f(u[j]) - ms.x) * ms.y : 0.0f;
                u[j] = f2b(x);
            }
        }
        ushort* xp = &Xs[tl * 1288 + (c * 8) * 40 + nn];
        #pragma unroll
        for (int j = 0; j < 8; ++j) xp[j * 40] = u[j];
    }
    __syncthreads();

    #pragma unroll
    for (int mh = 0; mh < 2; ++mh) {
        // ---- K-phase: per s, D[n=16][t=16] = Kmat[s](n,m) x X(m,t,s); K=m=32
        #pragma unroll
        for (int k = 0; k < 8; ++k) {
            const int sl = wv * 8 + k;
            const short8 af = *(const short8*)(Kmat + (size_t)(s0 + sl) * 1024 + (mh * 16 + frow) * 32 + quad * 8);
            const short8 bf = *(const short8*)&Xs[frow * 1288 + sl * 40 + quad * 8];
            floatx4 z = {0.f, 0.f, 0.f, 0.f};
            floatx4 d = __builtin_amdgcn_mfma_f32_16x16x32_bf16(af, bf, z, 0, 0, 0);
            *(floatx4*)&Kp[frow * 516 + sl * 16 + quad * 4] = d;
        }
        __syncthreads();

        // ---- C-phase: per t, D[s=16][n=16] = X(s,m,t) x Cmat[t](n,m); add Kp, mask, store
        #pragma unroll
        for (int i = 0; i < 4; ++i) {
            const int tl = wv * 4 + i;
            const int tg = t0 + tl;
            const short8 bf = *(const short8*)(Cmat + (size_t)tg * 1024 + (mh * 16 + frow) * 32 + quad * 8);
            #pragma unroll
            for (int st = 0; st < 2; ++st) {
                const short8 af = *(const short8*)&Xs[tl * 1288 + (st * 16 + frow) * 40 + quad * 8];
                floatx4 z = {0.f, 0.f, 0.f, 0.f};
                floatx4 d = __builtin_amdgcn_mfma_f32_16x16x32_bf16(af, bf, z, 0, 0, 0);
                float v[4];
                #pragma unroll
                for (int r = 0; r < 4; ++r) {
                    const int sl = st * 16 + quad * 4 + r;
                    float val = d[r] + Kp[tl * 516 + sl * 16 + frow];
                    v[r] = (s0 + sl > tg) ? 0.0f : val;
                }
                uint2 stv;
                stv.x = (unsigned)pack_bf16(v[0], v[1]);
                stv.y = (unsigned)pack_bf16(v[2], v[3]);
                *(uint2*)&Lb[((size_t)(mh * 16 + frow) * T_DIM + tg) * S_DIM + s0 + st * 16 + quad * 4] = stv;
            }
        }
        __syncthreads();   // Kp reused by next mh
    }
}

// ---------------------------------------------------------------------------
// av3: O = P V via MFMA. One block per (n, 16-t tile): grid 2048 blocks,
// whole grid resident (8 blocks/CU). The 4 waves split s with stride 4 and
// read A-frags DIRECTLY from P (64 B/row per instr, conflict-free, the
// round-1 win) -- no staging barriers. bf16 LDS partial reduction
// (round-0-proven, 17.4 KB keeps 8+ blocks/CU). Vt stays L2-hot: n fastest
// in grid -> XCD = n%8 -> 4 heads x 256 KB = 1 MB Vt working set per XCD L2.
// ---------------------------------------------------------------------------
__global__ __launch_bounds__(256, 4) void av3(const ushort* __restrict__ P,
                                              const ushort* __restrict__ Vt,
                                              float* __restrict__ O) {
    const int tid = threadIdx.x;
    const int wv = tid >> 6, ln = tid & 63;
    const int frow = ln & 15, quad = ln >> 4;
    const int n  = blockIdx.x;
    const int tt = 63 - blockIdx.y;      // big tiles first
    const int t0 = tt * 16;

    __shared__ ushort red[4][16][136];   // 17408 B bf16 partials

    const ushort* Pn  = P  + ((size_t)n * T_DIM + t0) * S_DIM;
    const ushort* Vtn = Vt + (size_t)n * D_HEAD * S_DIM;

    const int nsteps = (t0 + 47) >> 5;   // ceil((t0+16)/32)
    const int nclean = t0 >> 5;          // steps fully below diagonal

    floatx4 acc[8] = {};
    for (int sb = wv; sb < nsteps; sb += 4) {
        short8 a = *(const short8*)(Pn + (size_t)frow * S_DIM + sb * 32 + quad * 8);
        if (sb >= nclean) {
            const int tg  = t0 + frow;
            const int sg0 = sb * 32 + quad * 8;
            #pragma unroll
            for (int j = 0; j < 8; ++j)
                if (sg0 + j > tg) a[j] = 0;
        }
        #pragma unroll
        for (int dc = 0; dc < 8; ++dc) {
            const short8 b = *(const short8*)(Vtn + (size_t)(dc * 16 + frow) * S_DIM + sb * 32 + quad * 8);
            acc[dc] = __builtin_amdgcn_mfma_f32_16x16x32_bf16(a, b, acc[dc], 0, 0, 0);
        }
    }

    #pragma unroll
    for (int dc = 0; dc < 8; ++dc)
        #pragma unroll
        for (int r = 0; r < 4; ++r)
            red[wv][quad * 4 + r][dc * 16 + frow] = f2b(acc[dc][r]);
    __syncthreads();

    #pragma unroll
    for (int it = 0; it < 2; ++it) {
        int idx = tid + it * 256;
        int d4 = idx & 31, tr = idx >> 5;
        float4 v;
        v.x = b2f(red[0][tr][d4 * 4 + 0]) + b2f(red[1][tr][d4 * 4 + 0]) + b2f(red[2][tr][d4 * 4 + 0]) + b2f(red[3][tr][d4 * 4 + 0]);
        v.y = b2f(red[0][tr][d4 * 4 + 1]) + b2f(red[1][tr][d4 * 4 + 1]) + b2f(red[2][tr][d4 * 4 + 1]) + b2f(red[3][tr][d4 * 4 + 1]);
        v.z = b2f(red[0][tr][d4 * 4 + 2]) + b2f(red[1][tr][d4 * 4 + 2]) + b2f(red[2][tr][d4 * 4 + 2]) + b2f(red[3][tr][d4 * 4 + 2]);
        v.w = b2f(red[0][tr][d4 * 4 + 3]) + b2f(red[1][tr][d4 * 4 + 3]) + b2f(red[2][tr][d4 * 4 + 3]) + b2f(red[3][tr][d4 * 4 + 3]);
        *(float4*)&O[((size_t)n * T_DIM + t0 + tr) * D_HEAD + d4 * 4] = v;
    }
}

// ---------------------------------------------------------------------------
extern "C" void kernel_launch(void* const* d_in, const int* in_sizes, int n_in,
                              void* d_out, int out_size, void* d_ws, size_t ws_size,
                              hipStream_t stream) {
    const float* Q    = (const float*)d_in[0];
    const float* K    = (const float*)d_in[1];
    const float* V    = (const float*)d_in[2];
    const float* sw_pre  = (const float*)d_in[4];
    const float* qw1_pre = (const float*)d_in[5];
    const float* qw2_pre = (const float*)d_in[6];
    const float* kw1_pre = (const float*)d_in[7];
    const float* kw2_pre = (const float*)d_in[8];
    const float* qdd_pre = (const float*)d_in[9];
    const float* kdd_pre = (const float*)d_in[10];
    const float* sw_post  = (const float*)d_in[11];
    const float* qw1_post = (const float*)d_in[12];
    const float* qw2_post = (const float*)d_in[13];
    const float* kw1_post = (const float*)d_in[14];
    const float* kw2_post = (const float*)d_in[15];
    const float* qdd_post = (const float*)d_in[16];
    const float* kdd_post = (const float*)d_in[17];

    // ws: L bf16 [32][1024][1024] = 64 MB, then Vt bf16 [32][128][1024] = 8 MB
    ushort* Lb = (ushort*)d_ws;
    ushort* Vt = (ushort*)((char*)d_ws + (size_t)N_HEADS * T_DIM * S_DIM * 2);
    float*  O  = (float*)d_out;

    // d_out scratch (16 MB): mats in first 8 MB, softmax stats after.
    // Both fully consumed before av3 overwrites d_out.
    ushort* mats  = (ushort*)d_out;
    ushort* Cpre  = mats + 0 * 1024 * 1024;
    ushort* Kpre  = mats + 1 * 1024 * 1024;
    ushort* Cpost = mats + 2 * 1024 * 1024;
    ushort* Kpost = mats + 3 * 1024 * 1024;
    float2* stats = (float2*)((char*)d_out + (size_t)8 * 1024 * 1024);

    mat4_kernel<<<dim3(1024, 4), 256, 0, stream>>>(
        sw_pre, qw1_pre, qw2_pre, qdd_pre, kw1_pre, kw2_pre, kdd_pre,
        sw_post, qw1_post, qw2_post, qdd_post, kw1_post, kw2_post, kdd_post, mats);
    vt_kernel<<<dim3(16, 32), 256, 0, stream>>>(V, Vt);

    qk_mfma<<<dim3(16, 16, 32), 256, 0, stream>>>(Q, K, Lb);
    proj2t<false><<<dim3(32, 64), 256, 0, stream>>>(Lb, Cpre, Kpre, nullptr);
    rowstat<<<dim3(8192), 256, 0, stream>>>(Lb, stats);
    proj2t<true><<<dim3(32, 64), 256, 0, stream>>>(Lb, Cpost, Kpost, stats);
    av3<<<dim3(32, 64), 256, 0, stream>>>(Lb, Vt, O);
}